// Round 11
// baseline (280.794 us; speedup 1.0000x reference)
//
#include <hip/hip_runtime.h>
#include <hip/hip_bf16.h>
#include <cfloat>

#define N_NODES 50000
#define N_EDGES 800000
#define E_TOT   850000   /* edges + self-loops */
#define NEG_SLOPE 0.2f
#define SM_EPS 1e-16f
#define SCAN_B 196       /* ceil(50000/256) */
#define LOG2E 1.4426950408889634f

/* counting-sort geometry: 32 edge chunks x 16 node ranges */
#define NCH 32
#define CSZ 25000        /* N_EDGES / NCH */
#define NR  16
#define RSZ 3125         /* N_NODES / NR */

typedef __attribute__((ext_vector_type(8))) short short8;
typedef __attribute__((ext_vector_type(4))) float f32x4;

__device__ __forceinline__ float lrelu(float v) { return v > 0.0f ? v : NEG_SLOPE * v; }

// fp32 -> bf16 (RNE) pack / unpack helpers
__device__ __forceinline__ unsigned f2bf_pack2(float a, float b) {
    unsigned ua = __float_as_uint(a);
    ua += 0x7fff + ((ua >> 16) & 1);
    unsigned ub = __float_as_uint(b);
    ub += 0x7fff + ((ub >> 16) & 1);
    return (ua >> 16) | (ub & 0xffff0000u);
}
__device__ __forceinline__ unsigned short f2bf(float a) {
    unsigned ua = __float_as_uint(a);
    ua += 0x7fff + ((ua >> 16) & 1);
    return (unsigned short)(ua >> 16);
}
__device__ __forceinline__ float bf_lo(unsigned u) { return __uint_as_float(u << 16); }
__device__ __forceinline__ float bf_hi(unsigned u) { return __uint_as_float(u & 0xffff0000u); }

// ---- prep: pack Bp1/Bp2/Wc1p into MFMA B lane order; zero flags ----
__device__ __forceinline__ unsigned short pack_one(const float* __restrict__ B0,
                                                   const float* __restrict__ B1,
                                                   int i, int N) {
    int m   = i / (128 * N);
    int rem = i % (128 * N);
    int j    = rem & 7;
    int quad = (rem >> 3) & 3;
    int n    = (rem >> 5) & 15;
    int ctk  = rem >> 9;
    int ct   = ctk % (N / 16);
    int kt   = ctk / (N / 16);
    int k    = kt * 32 + quad * 8 + j;
    int col  = ct * 16 + n;
    const float* B = m ? B1 : B0;
    return f2bf(B[k * N + col]);
}

__global__ void prep(const float* __restrict__ Wl1, const float* __restrict__ Wr1,
                     const float* __restrict__ Wl2, const float* __restrict__ Wr2,
                     const float* __restrict__ Wc1,
                     unsigned short* __restrict__ Bp1, unsigned short* __restrict__ Bp2,
                     unsigned short* __restrict__ Wc1p,
                     int* __restrict__ flags) {
    int i = blockIdx.x * 256 + threadIdx.x;
    if (i < 32768) {
        Bp1[i] = pack_one(Wl1, Wr1, i, 128);
    } else if (i < 49152) {
        Bp2[i - 32768] = pack_one(Wl2, Wr2, i - 32768, 64);
    } else if (i < 57344) {
        // Wc1 [64][128] -> B fragments, K=64 (kt<2), N=128
        int idx = i - 49152;
        int j    = idx & 7;
        int quad = (idx >> 3) & 3;
        int n    = (idx >> 5) & 15;
        int ctk  = idx >> 9;
        int ct   = ctk & 7;
        int kt   = ctk >> 3;
        Wc1p[idx] = f2bf(Wc1[(kt * 32 + quad * 8 + j) * 128 + ct * 16 + n]);
    } else if (i < 57600) {
        flags[i - 57344] = 0;
    }
}

// ---- GEMM wave body: BOTH matrix halves of layer-1 GEMM (A loaded+converted once) ----
__device__ __forceinline__ void gemm128_both(int b, const float* __restrict__ x,
                                             const unsigned short* __restrict__ Bp1,
                                             unsigned short* __restrict__ xlbf,
                                             float* __restrict__ xr1, int M) {
    int w = threadIdx.x >> 6, lane = threadIdx.x & 63;
    int quad = lane >> 4, l16 = lane & 15;
    int row0 = b * 32 + (w & 1) * 16;
    int cb   = (w >> 1) * 64;
    f32x4 accL[4], accR[4];
    #pragma unroll
    for (int t = 0; t < 4; ++t) {
        accL[t] = (f32x4){0.f, 0.f, 0.f, 0.f};
        accR[t] = (f32x4){0.f, 0.f, 0.f, 0.f};
    }
    int arow = row0 + l16;
    bool aok = arow < M;
    #pragma unroll
    for (int kt = 0; kt < 4; ++kt) {
        short8 a = (short8)0;
        if (aok) {
            const float* Ap = x + (size_t)arow * 128 + quad * 8 + kt * 32;
            float4 f0 = *(const float4*)(Ap);
            float4 f1 = *(const float4*)(Ap + 4);
            union { uint4 u; short8 s; } cv;
            cv.u.x = f2bf_pack2(f0.x, f0.y);
            cv.u.y = f2bf_pack2(f0.z, f0.w);
            cv.u.z = f2bf_pack2(f1.x, f1.y);
            cv.u.w = f2bf_pack2(f1.z, f1.w);
            a = cv.s;
        }
        #pragma unroll
        for (int t = 0; t < 4; ++t) {
            int ct = (cb >> 4) + t;
            const short* bp = (const short*)Bp1 + (((kt * 8 + ct) * 16 + l16) * 4 + quad) * 8;
            short8 bL = *(const short8*)bp;
            short8 bR = *(const short8*)(bp + 128 * 128);
            accL[t] = __builtin_amdgcn_mfma_f32_16x16x32_bf16(a, bL, accL[t], 0, 0, 0);
            accR[t] = __builtin_amdgcn_mfma_f32_16x16x32_bf16(a, bR, accR[t], 0, 0, 0);
        }
    }
    #pragma unroll
    for (int t = 0; t < 4; ++t) {
        int col = cb + t * 16 + l16;
        #pragma unroll
        for (int r = 0; r < 4; ++r) {
            int row = row0 + quad * 4 + r;
            if (row < M) {
                xlbf[(size_t)row * 128 + col] = f2bf(accL[t][r]);
                xr1[(size_t)row * 128 + col]  = accR[t][r];
            }
        }
    }
}

// ---- K2: LDS-histogram count (32-bit counters, 16 ranges) ⊕ fused xl+xr GEMM ----
__global__ __launch_bounds__(256)
void k2_count_gemms(const int* __restrict__ ei, unsigned* __restrict__ hist,
                    unsigned short* __restrict__ rank16,
                    const float* __restrict__ x, const unsigned short* __restrict__ Bp1,
                    unsigned short* __restrict__ xlbf, float* __restrict__ xr1, int M) {
    __shared__ unsigned hcnt[RSZ];            // 3125 words = 12.5 KB
    int b = blockIdx.x;
    if (b < NR * NCH) {
        int r = b >> 5, c = b & 31;
        for (int i = threadIdx.x; i < RSZ; i += 256) hcnt[i] = 0;
        int nz = __syncthreads_or(ei[2 * threadIdx.x + 1]);   // barrier + layout probe (0 => int64)
        int nlo = r * RSZ, nhi = nlo + RSZ;
        int cbeg = c * CSZ, cend = cbeg + CSZ;
        // 4 consecutive edges per thread per iteration (256 threads x 4 = 1024/sweep)
        for (int e4 = cbeg + (int)threadIdx.x * 4; e4 < cend; e4 += 1024) {
            int d0, d1, d2, d3;
            if (nz) {
                int4 dp = *(const int4*)(ei + N_EDGES + e4);
                d0 = dp.x; d1 = dp.y; d2 = dp.z; d3 = dp.w;
            } else {
                int4 a0 = *(const int4*)(ei + 2 * N_EDGES + 2 * e4);
                int4 a1 = *(const int4*)(ei + 2 * N_EDGES + 2 * e4 + 4);
                d0 = a0.x; d1 = a0.z; d2 = a1.x; d3 = a1.z;
            }
            int dd[4] = {d0, d1, d2, d3};
            #pragma unroll
            for (int j = 0; j < 4; ++j) {
                int d = dd[j];
                if (d >= nlo && d < nhi) {
                    unsigned rk = atomicAdd(&hcnt[d - nlo], 1u);
                    rank16[e4 + j] = (unsigned short)rk;
                }
            }
        }
        __syncthreads();
        unsigned* hp = hist + (size_t)(r * NCH + c) * RSZ;
        for (int i = threadIdx.x; i < RSZ; i += 256) hp[i] = hcnt[i];
    } else {
        gemm128_both(b - NR * NCH, x, Bp1, xlbf, xr1, M);
    }
}

// ---- scan (fused; publish/spin over block sums); sums NCH chunk-counts per node,
//      emits rowptr + per-(range,chunk,node) scatter bases ----
__global__ void scan_fused(const unsigned* __restrict__ hist, int* __restrict__ rowptr,
                           int* __restrict__ esrc, int* __restrict__ bsum,
                           int* __restrict__ flags, int* __restrict__ base) {
    __shared__ int sh[256];
    int b = blockIdx.x, t = threadIdx.x, i = b * 256 + t;
    unsigned d[NCH];
    int tot = 0;
    int rr = 0, q = 0;
    if (i < N_NODES) {
        rr = i / RSZ; q = i - rr * RSZ;
        const unsigned* hp = hist + (size_t)rr * NCH * RSZ + q;
        #pragma unroll
        for (int c = 0; c < NCH; ++c) { d[c] = hp[(size_t)c * RSZ]; tot += (int)d[c]; }
    }
    int v = (i < N_NODES) ? tot + 1 : 0;
    sh[t] = v;
    __syncthreads();
    int val = v;
    for (int off = 1; off < 256; off <<= 1) {
        int add = (t >= off) ? sh[t - off] : 0;
        __syncthreads();
        val += add; sh[t] = val;
        __syncthreads();
    }
    if (t == 255) {
        bsum[b] = val;
        __threadfence();
        atomicExch(&flags[b], 1);
    }
    int contrib = 0;
    if (t < b) {
        while (atomicAdd(&flags[t], 0) == 0) {}
        contrib = atomicAdd(&bsum[t], 0);
    }
    __syncthreads();
    sh[t] = contrib;
    __syncthreads();
    #pragma unroll
    for (int off = 128; off; off >>= 1) {
        if (t < off) sh[t] += sh[t + off];
        __syncthreads();
    }
    int offset = sh[0];
    if (i < N_NODES) {
        int rp = (val - v) + offset;
        rowptr[i] = rp;
        esrc[rp] = i;       // self-loop first
        int acc = rp + 1;
        int* bp = base + (size_t)rr * NCH * RSZ + q;
        #pragma unroll
        for (int c = 0; c < NCH; ++c) { bp[(size_t)c * RSZ] = acc; acc += (int)d[c]; }
    }
    if (i == 0) rowptr[N_NODES] = E_TOT;
}

// ---- scatter: no atomics, position = base[range(dst)][chunk(e)][dst%RSZ] + rank ----
__global__ void scatter_edges(const int* __restrict__ ei, const int* __restrict__ base,
                              const unsigned short* __restrict__ rank16,
                              int* __restrict__ esrc) {
    int nz = __syncthreads_or(ei[2 * threadIdx.x + 1]);
    int i = blockIdx.x * blockDim.x + threadIdx.x;
    if (2 * i >= N_EDGES) return;
    bool has2 = (2 * i + 1 < N_EDGES);
    int s0, d0, s1 = 0, d1 = 0;
    if (nz) {
        int2 sp = *(const int2*)(ei + 2 * i);
        int2 dp = *(const int2*)(ei + N_EDGES + 2 * i);
        s0 = sp.x; s1 = sp.y; d0 = dp.x; d1 = dp.y;
    } else {
        int4 sp = *(const int4*)(ei + 4 * i);
        int4 dp = *(const int4*)(ei + 2 * N_EDGES + 4 * i);
        s0 = sp.x; s1 = sp.z; d0 = dp.x; d1 = dp.z;
    }
    unsigned rr = *(const unsigned*)(rank16 + 2 * i);
    int e0 = 2 * i, e1 = 2 * i + 1;
    int c0 = e0 / CSZ, c1 = e1 / CSZ;
    int r0 = d0 / RSZ, r1 = d1 / RSZ;
    esrc[base[((size_t)r0 * NCH + c0) * RSZ + (d0 - r0 * RSZ)] + (int)(rr & 0xffffu)] = s0;
    if (has2)
        esrc[base[((size_t)r1 * NCH + c1) * RSZ + (d1 - r1 * RSZ)] + (int)(rr >> 16)] = s1;
}

// ---- layer 2 GEMM (N=64): C0bf = bf16(A@B0), C1 = A@B1 (fp32) ----
__global__ __launch_bounds__(256)
void gemm_mfma64(const unsigned short* __restrict__ Abf, const unsigned short* __restrict__ Bp,
                 unsigned short* __restrict__ C0bf, float* __restrict__ C1, int M) {
    int w = threadIdx.x >> 6, lane = threadIdx.x & 63;
    int quad = lane >> 4, l16 = lane & 15;
    int matrix = w >> 1;
    int row0 = blockIdx.x * 32 + (w & 1) * 16;
    const unsigned short* Bm = Bp + matrix * 128 * 64;
    f32x4 acc[4];
    #pragma unroll
    for (int t = 0; t < 4; ++t) acc[t] = (f32x4){0.f, 0.f, 0.f, 0.f};
    int arow = row0 + l16;
    bool aok = arow < M;
    const short* Ap = (const short*)Abf + (size_t)arow * 128 + quad * 8;
    #pragma unroll
    for (int kt = 0; kt < 4; ++kt) {
        short8 a = (short8)0;
        if (aok) a = *(const short8*)(Ap + kt * 32);
        #pragma unroll
        for (int t = 0; t < 4; ++t) {
            const short* bp = (const short*)Bm + (((kt * 4 + t) * 16 + l16) * 4 + quad) * 8;
            short8 bfr = *(const short8*)bp;
            acc[t] = __builtin_amdgcn_mfma_f32_16x16x32_bf16(a, bfr, acc[t], 0, 0, 0);
        }
    }
    #pragma unroll
    for (int t = 0; t < 4; ++t) {
        int col = t * 16 + l16;
        #pragma unroll
        for (int r = 0; r < 4; ++r) {
            int row = row0 + quad * 4 + r;
            if (row < M) {
                if (matrix) C1[(size_t)row * 64 + col] = acc[t][r];
                else        C0bf[(size_t)row * 64 + col] = f2bf(acc[t][r]);
            }
        }
    }
}

// ---------------- Layer 1 (H=8, C=16) — 1 wave/node, unroll-2 dual-prefetch ----------------
// lrelu(t) = 0.6t + 0.4|t| (slope 0.2); 0.6/0.4 and log2(e) folded into att coeffs.
__global__ __launch_bounds__(64)
void node_fused1(const int* __restrict__ rowptr, const int* __restrict__ esrc,
                 const unsigned short* __restrict__ xlbf, const float* __restrict__ xr,
                 const float* __restrict__ att, const float* __restrict__ b1,
                 unsigned short* __restrict__ hbf) {
    int lane = threadIdx.x;                   // 0..63
    int n = blockIdx.x;                       // grid = 50000 exact
    int slot = lane >> 4;                     // 0..3
    int l = lane & 15;                        // channels 8l..8l+7
    int beg = rowptr[n], end = rowptr[n + 1];
    const float* xrp = xr + (size_t)n * 128 + 8 * l;
    float4 xra = *(const float4*)(xrp);
    float4 xrb = *(const float4*)(xrp + 4);
    float4 ata = *(const float4*)(att + 8 * l);
    float4 atb = *(const float4*)(att + 8 * l + 4);
    const float c6 = 0.6f * LOG2E, c4 = 0.4f * LOG2E;
    float4 a6, a4, b6, b4c;
    a6.x = ata.x * c6; a6.y = ata.y * c6; a6.z = ata.z * c6; a6.w = ata.w * c6;
    a4.x = ata.x * c4; a4.y = ata.y * c4; a4.z = ata.z * c4; a4.w = ata.w * c4;
    b6.x = atb.x * c6; b6.y = atb.y * c6; b6.z = atb.z * c6; b6.w = atb.w * c6;
    b4c.x = atb.x * c4; b4c.y = atb.y * c4; b4c.z = atb.z * c4; b4c.w = atb.w * c4;
    float den = 0.0f;
    float4 aa = {0, 0, 0, 0}, ab = {0, 0, 0, 0};

    const unsigned loff = 8u * (unsigned)l;
    auto ldrow = [&](unsigned s) -> uint4 {
        return *(const uint4*)(xlbf + (s * 128u + loff));   // 32-bit offset, saddr form
    };
    auto edge = [&](const uint4& u) {
        float x0 = bf_lo(u.x), x1 = bf_hi(u.x);
        float x2 = bf_lo(u.y), x3 = bf_hi(u.y);
        float x4 = bf_lo(u.z), x5 = bf_hi(u.z);
        float x6 = bf_lo(u.w), x7 = bf_hi(u.w);
        float t0 = x0 + xra.x, t1 = x1 + xra.y, t2 = x2 + xra.z, t3 = x3 + xra.w;
        float t4 = x4 + xrb.x, t5 = x5 + xrb.y, t6 = x6 + xrb.z, t7 = x7 + xrb.w;
        float v = 0.0f;
        v = __builtin_fmaf(a6.x, t0, v); v = __builtin_fmaf(a4.x, __builtin_fabsf(t0), v);
        v = __builtin_fmaf(a6.y, t1, v); v = __builtin_fmaf(a4.y, __builtin_fabsf(t1), v);
        v = __builtin_fmaf(a6.z, t2, v); v = __builtin_fmaf(a4.z, __builtin_fabsf(t2), v);
        v = __builtin_fmaf(a6.w, t3, v); v = __builtin_fmaf(a4.w, __builtin_fabsf(t3), v);
        v = __builtin_fmaf(b6.x, t4, v); v = __builtin_fmaf(b4c.x, __builtin_fabsf(t4), v);
        v = __builtin_fmaf(b6.y, t5, v); v = __builtin_fmaf(b4c.y, __builtin_fabsf(t5), v);
        v = __builtin_fmaf(b6.z, t6, v); v = __builtin_fmaf(b4c.z, __builtin_fabsf(t6), v);
        v = __builtin_fmaf(b6.w, t7, v); v = __builtin_fmaf(b4c.w, __builtin_fabsf(t7), v);
        v += __shfl_xor(v, 1);                // combine the head's two lanes
        float p = exp2f(v);
        den += p;
        aa.x = __builtin_fmaf(p, x0, aa.x); aa.y = __builtin_fmaf(p, x1, aa.y);
        aa.z = __builtin_fmaf(p, x2, aa.z); aa.w = __builtin_fmaf(p, x3, aa.w);
        ab.x = __builtin_fmaf(p, x4, ab.x); ab.y = __builtin_fmaf(p, x5, ab.y);
        ab.z = __builtin_fmaf(p, x6, ab.z); ab.w = __builtin_fmaf(p, x7, ab.w);
    };
    // prefetch indices clamp to beg (self-loop slot, always valid)
    int k0 = beg + slot;
    unsigned s0 = (unsigned)esrc[k0 < end ? k0 : beg];
    unsigned s1 = (unsigned)esrc[k0 + 4 < end ? k0 + 4 : beg];
    uint4 uA = ldrow(s0);
    uint4 uB = ldrow(s1);
    unsigned sC = (unsigned)esrc[k0 + 8 < end ? k0 + 8 : beg];
    unsigned sD = (unsigned)esrc[k0 + 12 < end ? k0 + 12 : beg];

    for (int k = k0; k < end; k += 8) {
        uint4 uC = ldrow(sC);                                    // rows 2 iters ahead
        uint4 uD = ldrow(sD);
        unsigned sE = (unsigned)esrc[k + 16 < end ? k + 16 : beg];
        unsigned sF = (unsigned)esrc[k + 20 < end ? k + 20 : beg];
        edge(uA);
        if (k + 4 < end) edge(uB);
        uA = uC; uB = uD; sC = sE; sD = sF;
    }

    #pragma unroll
    for (int off = 16; off < 64; off <<= 1) {
        aa.x += __shfl_xor(aa.x, off); aa.y += __shfl_xor(aa.y, off);
        aa.z += __shfl_xor(aa.z, off); aa.w += __shfl_xor(aa.w, off);
        ab.x += __shfl_xor(ab.x, off); ab.y += __shfl_xor(ab.y, off);
        ab.z += __shfl_xor(ab.z, off); ab.w += __shfl_xor(ab.w, off);
        den   += __shfl_xor(den, off);
    }
    if (slot == 0) {
        float inv = 1.0f / (den + SM_EPS);
        float4 b4a = *(const float4*)(b1 + 8 * l);
        float4 b4b = *(const float4*)(b1 + 8 * l + 4);
        float oa0 = fmaxf(aa.x * inv + b4a.x, 0.0f);
        float oa1 = fmaxf(aa.y * inv + b4a.y, 0.0f);
        float oa2 = fmaxf(aa.z * inv + b4a.z, 0.0f);
        float oa3 = fmaxf(aa.w * inv + b4a.w, 0.0f);
        float ob0 = fmaxf(ab.x * inv + b4b.x, 0.0f);
        float ob1 = fmaxf(ab.y * inv + b4b.y, 0.0f);
        float ob2 = fmaxf(ab.z * inv + b4b.z, 0.0f);
        float ob3 = fmaxf(ab.w * inv + b4b.w, 0.0f);
        uint4 pk;
        pk.x = f2bf_pack2(oa0, oa1);
        pk.y = f2bf_pack2(oa2, oa3);
        pk.z = f2bf_pack2(ob0, ob1);
        pk.w = f2bf_pack2(ob2, ob3);
        *(uint4*)(hbf + (size_t)n * 128 + 8 * l) = pk;
    }
}

// ---------------- Layer 2 (H=1, C=64) — 1 wave/node, unroll-2 dual-prefetch ----------------
__global__ __launch_bounds__(64)
void node_fused2(const int* __restrict__ rowptr, const int* __restrict__ esrc,
                 const unsigned short* __restrict__ xlbf, const float* __restrict__ xr,
                 const float* __restrict__ att, const float* __restrict__ b2v,
                 float* __restrict__ out_emb, unsigned short* __restrict__ embbf) {
    int lane = threadIdx.x;
    int n = blockIdx.x;
    int slot = lane >> 3;                     // 0..7
    int l = lane & 7;                         // channels 8l..8l+7
    int beg = rowptr[n], end = rowptr[n + 1];
    const float* xrp = xr + (size_t)n * 64 + 8 * l;
    float4 xra = *(const float4*)(xrp);
    float4 xrb = *(const float4*)(xrp + 4);
    float4 ata = *(const float4*)(att + 8 * l);
    float4 atb = *(const float4*)(att + 8 * l + 4);
    const float c6 = 0.6f * LOG2E, c4 = 0.4f * LOG2E;
    float4 a6, a4, b6, b4c;
    a6.x = ata.x * c6; a6.y = ata.y * c6; a6.z = ata.z * c6; a6.w = ata.w * c6;
    a4.x = ata.x * c4; a4.y = ata.y * c4; a4.z = ata.z * c4; a4.w = ata.w * c4;
    b6.x = atb.x * c6; b6.y = atb.y * c6; b6.z = atb.z * c6; b6.w = atb.w * c6;
    b4c.x = atb.x * c4; b4c.y = atb.y * c4; b4c.z = atb.z * c4; b4c.w = atb.w * c4;
    float den = 0.0f;
    float4 aa = {0, 0, 0, 0}, ab = {0, 0, 0, 0};

    const unsigned loff = 8u * (unsigned)l;
    auto ldrow = [&](unsigned s) -> uint4 {
        return *(const uint4*)(xlbf + (s * 64u + loff));     // 32-bit offset, saddr form
    };
    auto edge = [&](const uint4& u) {
        float x0 = bf_lo(u.x), x1 = bf_hi(u.x);
        float x2 = bf_lo(u.y), x3 = bf_hi(u.y);
        float x4 = bf_lo(u.z), x5 = bf_hi(u.z);
        float x6 = bf_lo(u.w), x7 = bf_hi(u.w);
        float t0 = x0 + xra.x, t1 = x1 + xra.y, t2 = x2 + xra.z, t3 = x3 + xra.w;
        float t4 = x4 + xrb.x, t5 = x5 + xrb.y, t6 = x6 + xrb.z, t7 = x7 + xrb.w;
        float v = 0.0f;
        v = __builtin_fmaf(a6.x, t0, v); v = __builtin_fmaf(a4.x, __builtin_fabsf(t0), v);
        v = __builtin_fmaf(a6.y, t1, v); v = __builtin_fmaf(a4.y, __builtin_fabsf(t1), v);
        v = __builtin_fmaf(a6.z, t2, v); v = __builtin_fmaf(a4.z, __builtin_fabsf(t2), v);
        v = __builtin_fmaf(a6.w, t3, v); v = __builtin_fmaf(a4.w, __builtin_fabsf(t3), v);
        v = __builtin_fmaf(b6.x, t4, v); v = __builtin_fmaf(b4c.x, __builtin_fabsf(t4), v);
        v = __builtin_fmaf(b6.y, t5, v); v = __builtin_fmaf(b4c.y, __builtin_fabsf(t5), v);
        v = __builtin_fmaf(b6.z, t6, v); v = __builtin_fmaf(b4c.z, __builtin_fabsf(t6), v);
        v = __builtin_fmaf(b6.w, t7, v); v = __builtin_fmaf(b4c.w, __builtin_fabsf(t7), v);
        v += __shfl_xor(v, 1);
        v += __shfl_xor(v, 2);
        v += __shfl_xor(v, 4);
        float p = exp2f(v);
        den += p;
        aa.x = __builtin_fmaf(p, x0, aa.x); aa.y = __builtin_fmaf(p, x1, aa.y);
        aa.z = __builtin_fmaf(p, x2, aa.z); aa.w = __builtin_fmaf(p, x3, aa.w);
        ab.x = __builtin_fmaf(p, x4, ab.x); ab.y = __builtin_fmaf(p, x5, ab.y);
        ab.z = __builtin_fmaf(p, x6, ab.z); ab.w = __builtin_fmaf(p, x7, ab.w);
    };
    int k0 = beg + slot;
    unsigned s0 = (unsigned)esrc[k0 < end ? k0 : beg];
    unsigned s1 = (unsigned)esrc[k0 + 8 < end ? k0 + 8 : beg];
    uint4 uA = ldrow(s0);
    uint4 uB = ldrow(s1);
    unsigned sC = (unsigned)esrc[k0 + 16 < end ? k0 + 16 : beg];
    unsigned sD = (unsigned)esrc[k0 + 24 < end ? k0 + 24 : beg];

    for (int k = k0; k < end; k += 16) {
        uint4 uC = ldrow(sC);
        uint4 uD = ldrow(sD);
        unsigned sE = (unsigned)esrc[k + 32 < end ? k + 32 : beg];
        unsigned sF = (unsigned)esrc[k + 40 < end ? k + 40 : beg];
        edge(uA);
        if (k + 8 < end) edge(uB);
        uA = uC; uB = uD; sC = sE; sD = sF;
    }

    #pragma unroll
    for (int off = 8; off < 64; off <<= 1) {
        aa.x += __shfl_xor(aa.x, off); aa.y += __shfl_xor(aa.y, off);
        aa.z += __shfl_xor(aa.z, off); aa.w += __shfl_xor(aa.w, off);
        ab.x += __shfl_xor(ab.x, off); ab.y += __shfl_xor(ab.y, off);
        ab.z += __shfl_xor(ab.z, off); ab.w += __shfl_xor(ab.w, off);
        den   += __shfl_xor(den, off);
    }
    if (slot == 0) {
        float inv = 1.0f / (den + SM_EPS);
        float4 b4a = *(const float4*)(b2v + 8 * l);
        float4 b4b = *(const float4*)(b2v + 8 * l + 4);
        float4 ea, eb;
        ea.x = aa.x * inv + b4a.x; ea.y = aa.y * inv + b4a.y;
        ea.z = aa.z * inv + b4a.z; ea.w = aa.w * inv + b4a.w;
        eb.x = ab.x * inv + b4b.x; eb.y = ab.y * inv + b4b.y;
        eb.z = ab.z * inv + b4b.z; eb.w = ab.w * inv + b4b.w;
        float* op = out_emb + (size_t)n * 64 + 8 * l;
        *(float4*)(op)     = ea;
        *(float4*)(op + 4) = eb;
        uint4 pk;
        pk.x = f2bf_pack2(ea.x, ea.y);
        pk.y = f2bf_pack2(ea.z, ea.w);
        pk.z = f2bf_pack2(eb.x, eb.y);
        pk.w = f2bf_pack2(eb.z, eb.w);
        *(uint4*)(embbf + (size_t)n * 64 + 8 * l) = pk;
    }
}

// ---------------- Classifier via MFMA ----------------
__global__ __launch_bounds__(256)
void cls_mfma(const unsigned short* __restrict__ embbf, const unsigned short* __restrict__ Wc1p,
              const float* __restrict__ bc1, const float* __restrict__ Wc2,
              const float* __restrict__ bc2, float* __restrict__ out_logits) {
    __shared__ float part[2][16][2][2];       // [rowhalf][row16][colhalf][class]
    int w = threadIdx.x >> 6, lane = threadIdx.x & 63;
    int quad = lane >> 4, l16 = lane & 15;
    int rowhalf = w & 1, colhalf = w >> 1;
    int row0 = blockIdx.x * 32 + rowhalf * 16;
    int cb = colhalf * 64;
    f32x4 acc[4];
    #pragma unroll
    for (int t = 0; t < 4; ++t) acc[t] = (f32x4){0.f, 0.f, 0.f, 0.f};
    int arow = row0 + l16;
    bool aok = arow < N_NODES;
    const short* Ap = (const short*)embbf + (size_t)arow * 64 + quad * 8;
    #pragma unroll
    for (int kt = 0; kt < 2; ++kt) {
        short8 a = (short8)0;
        if (aok) a = *(const short8*)(Ap + kt * 32);
        #pragma unroll
        for (int t = 0; t < 4; ++t) {
            int ct = colhalf * 4 + t;
            const short* bp = (const short*)Wc1p + (((kt * 8 + ct) * 16 + l16) * 4 + quad) * 8;
            short8 bfr = *(const short8*)bp;
            acc[t] = __builtin_amdgcn_mfma_f32_16x16x32_bf16(a, bfr, acc[t], 0, 0, 0);
        }
    }
    float p0[4] = {0, 0, 0, 0}, p1[4] = {0, 0, 0, 0};
    #pragma unroll
    for (int t = 0; t < 4; ++t) {
        int col = cb + t * 16 + l16;
        float w2a = Wc2[2 * col], w2b = Wc2[2 * col + 1];
        float bc = bc1[col];
        #pragma unroll
        for (int r = 0; r < 4; ++r) {
            float tv = fmaxf(acc[t][r] + bc, 0.0f);
            p0[r] += tv * w2a;
            p1[r] += tv * w2b;
        }
    }
    #pragma unroll
    for (int off = 1; off < 16; off <<= 1) {
        #pragma unroll
        for (int r = 0; r < 4; ++r) {
            p0[r] += __shfl_xor(p0[r], off);
            p1[r] += __shfl_xor(p1[r], off);
        }
    }
    if (l16 == 0) {
        #pragma unroll
        for (int r = 0; r < 4; ++r) {
            part[rowhalf][quad * 4 + r][colhalf][0] = p0[r];
            part[rowhalf][quad * 4 + r][colhalf][1] = p1[r];
        }
    }
    __syncthreads();
    int t = threadIdx.x;
    if (t < 64) {
        int row = t >> 1, c = t & 1;
        int rh = row >> 4, r16 = row & 15;
        float s = part[rh][r16][0][c] + part[rh][r16][1][c] + bc2[c];
        int n = blockIdx.x * 32 + row;
        if (n < N_NODES) out_logits[(size_t)n * 2 + c] = s;
    }
}

extern "C" void kernel_launch(void* const* d_in, const int* in_sizes, int n_in,
                              void* d_out, int out_size, void* d_ws, size_t ws_size,
                              hipStream_t stream) {
    const float* x    = (const float*)d_in[0];
    const int*   ei   = (const int*)d_in[1];
    const float* Wl1  = (const float*)d_in[3];
    const float* Wr1  = (const float*)d_in[4];
    const float* att1 = (const float*)d_in[5];
    const float* b1   = (const float*)d_in[6];
    const float* Wl2  = (const float*)d_in[7];
    const float* Wr2  = (const float*)d_in[8];
    const float* att2 = (const float*)d_in[9];
    const float* b2   = (const float*)d_in[10];
    const float* Wc1  = (const float*)d_in[15];
    const float* bc1  = (const float*)d_in[16];
    const float* Wc2  = (const float*)d_in[17];
    const float* bc2  = (const float*)d_in[18];

    float* ws = (float*)d_ws;
    int* rowptr = (int*)ws + 50000;                //  50000 .. 100016
    int* esrc   = rowptr + 50016;                  // 100016 .. 950016
    int* bsum   = esrc + 850000;                   // 950016 .. 950272
    int* flags  = bsum + 256;                      // 950272 .. 950528
    unsigned short* rank16 = (unsigned short*)(flags + 256);   // 950528 .. 1350528 (400000 words)
    float* xr1           = ws + 1400448;                       // 6.4M words (layer2 xr2 in first 3.2M)
    unsigned short* xlbf = (unsigned short*)(ws + 7800448);    // 3.2M words (layer2 xl2 reuses)
    unsigned short* hbf  = (unsigned short*)(ws + 11000448);   // 3.2M words
    // hist/base overlay the hbf region: both dead before node_fused1 writes hbf.
    unsigned* hist = (unsigned*)(ws + 11000448);               // 1.6M words (512 blocks x 3125)
    int* base      = (int*)(ws + 12600448);                    // 1.6M words (.. 14200448)
    unsigned short* Bp1   = (unsigned short*)(ws + 14200448);  // .. 14216832
    unsigned short* Bp2   = (unsigned short*)(ws + 14216832);  // .. 14225024
    unsigned short* Wc1p  = (unsigned short*)(ws + 14225024);  // .. 14229120
    unsigned short* embbf = (unsigned short*)(ws + 14229120);  // 1.6M words
    // total ≈ 15.83M words ≈ 63 MB (unchanged)

    float* out_emb    = (float*)d_out;
    float* out_logits = out_emb + (size_t)N_NODES * 64;

    // ---- prep: pack Bp1/Bp2/Wc1p, zero flags (hist needs no zeroing: fully overwritten) ----
    prep<<<225, 256, 0, stream>>>(Wl1, Wr1, Wl2, Wr2, Wc1, Bp1, Bp2, Wc1p, flags);

    // ---- K2: LDS-hist count (16 ranges x 32 chunks, 32-bit counters) ⊕ fused xl+xr GEMM ----
    k2_count_gemms<<<NR * NCH + 1563, 256, 0, stream>>>(ei, hist, rank16, x, Bp1, xlbf, xr1, N_NODES);

    // ---- scan (sums 32 chunk counts/node, emits rowptr + base table) ----
    scan_fused<<<SCAN_B, 256, 0, stream>>>(hist, rowptr, esrc, bsum, flags, base);

    // ---- scatter (atomic-free) ----
    scatter_edges<<<1563, 256, 0, stream>>>(ei, base, rank16, esrc);

    // ---- layer 1 node pass: 1 wave per node, independent retirement ----
    node_fused1<<<50000, 64, 0, stream>>>(rowptr, esrc, xlbf, xr1, att1, b1, hbf);

    // ---- layer 2 ----
    gemm_mfma64<<<1563, 256, 0, stream>>>(hbf, Bp2, xlbf, xr1, N_NODES);
    node_fused2<<<50000, 64, 0, stream>>>(rowptr, esrc, xlbf, xr1, att2, b2, out_emb, embbf);

    // ---- classifier (MFMA) ----
    cls_mfma<<<1563, 256, 0, stream>>>(embbf, Wc1p, bc1, Wc2, bc2, out_logits);
}

// Round 12
// 264.800 us; speedup vs baseline: 1.0604x; 1.0604x over previous
//
#include <hip/hip_runtime.h>
#include <hip/hip_bf16.h>
#include <cfloat>

#define N_NODES 50000
#define N_EDGES 800000
#define E_TOT   850000   /* edges + self-loops */
#define NEG_SLOPE 0.2f
#define SM_EPS 1e-16f
#define SCAN_B 196       /* ceil(50000/256) */
#define LOG2E 1.4426950408889634f

/* counting-sort geometry: 32 edge chunks x 4 node ranges */
#define NCH 32
#define CSZ 25000        /* N_EDGES / NCH */
#define NR  4
#define RSZ 12500        /* N_NODES / NR */

typedef __attribute__((ext_vector_type(8))) short short8;
typedef __attribute__((ext_vector_type(4))) float f32x4;

__device__ __forceinline__ float lrelu(float v) { return v > 0.0f ? v : NEG_SLOPE * v; }

// fp32 -> bf16 (RNE) pack / unpack helpers
__device__ __forceinline__ unsigned f2bf_pack2(float a, float b) {
    unsigned ua = __float_as_uint(a);
    ua += 0x7fff + ((ua >> 16) & 1);
    unsigned ub = __float_as_uint(b);
    ub += 0x7fff + ((ub >> 16) & 1);
    return (ua >> 16) | (ub & 0xffff0000u);
}
__device__ __forceinline__ unsigned short f2bf(float a) {
    unsigned ua = __float_as_uint(a);
    ua += 0x7fff + ((ua >> 16) & 1);
    return (unsigned short)(ua >> 16);
}
__device__ __forceinline__ float bf_lo(unsigned u) { return __uint_as_float(u << 16); }
__device__ __forceinline__ float bf_hi(unsigned u) { return __uint_as_float(u & 0xffff0000u); }

// ---- prep: pack Bp1/Bp2/Wc1p into MFMA B lane order; zero flags ----
__device__ __forceinline__ unsigned short pack_one(const float* __restrict__ B0,
                                                   const float* __restrict__ B1,
                                                   int i, int N) {
    int m   = i / (128 * N);
    int rem = i % (128 * N);
    int j    = rem & 7;
    int quad = (rem >> 3) & 3;
    int n    = (rem >> 5) & 15;
    int ctk  = rem >> 9;
    int ct   = ctk % (N / 16);
    int kt   = ctk / (N / 16);
    int k    = kt * 32 + quad * 8 + j;
    int col  = ct * 16 + n;
    const float* B = m ? B1 : B0;
    return f2bf(B[k * N + col]);
}

__global__ void prep(const float* __restrict__ Wl1, const float* __restrict__ Wr1,
                     const float* __restrict__ Wl2, const float* __restrict__ Wr2,
                     const float* __restrict__ Wc1,
                     unsigned short* __restrict__ Bp1, unsigned short* __restrict__ Bp2,
                     unsigned short* __restrict__ Wc1p,
                     int* __restrict__ flags) {
    int i = blockIdx.x * 256 + threadIdx.x;
    if (i < 32768) {
        Bp1[i] = pack_one(Wl1, Wr1, i, 128);
    } else if (i < 49152) {
        Bp2[i - 32768] = pack_one(Wl2, Wr2, i - 32768, 64);
    } else if (i < 57344) {
        // Wc1 [64][128] -> B fragments, K=64 (kt<2), N=128
        int idx = i - 49152;
        int j    = idx & 7;
        int quad = (idx >> 3) & 3;
        int n    = (idx >> 5) & 15;
        int ctk  = idx >> 9;
        int ct   = ctk & 7;
        int kt   = ctk >> 3;
        Wc1p[idx] = f2bf(Wc1[(kt * 32 + quad * 8 + j) * 128 + ct * 16 + n]);
    } else if (i < 57600) {
        flags[i - 57344] = 0;
    }
}

// ---- GEMM wave body: BOTH matrix halves of layer-1 GEMM (A loaded+converted once) ----
__device__ __forceinline__ void gemm128_both(int b, const float* __restrict__ x,
                                             const unsigned short* __restrict__ Bp1,
                                             unsigned short* __restrict__ xlbf,
                                             float* __restrict__ xr1, int M) {
    int w = threadIdx.x >> 6, lane = threadIdx.x & 63;
    int quad = lane >> 4, l16 = lane & 15;
    int row0 = b * 32 + (w & 1) * 16;
    int cb   = (w >> 1) * 64;
    f32x4 accL[4], accR[4];
    #pragma unroll
    for (int t = 0; t < 4; ++t) {
        accL[t] = (f32x4){0.f, 0.f, 0.f, 0.f};
        accR[t] = (f32x4){0.f, 0.f, 0.f, 0.f};
    }
    int arow = row0 + l16;
    bool aok = arow < M;
    #pragma unroll
    for (int kt = 0; kt < 4; ++kt) {
        short8 a = (short8)0;
        if (aok) {
            const float* Ap = x + (size_t)arow * 128 + quad * 8 + kt * 32;
            float4 f0 = *(const float4*)(Ap);
            float4 f1 = *(const float4*)(Ap + 4);
            union { uint4 u; short8 s; } cv;
            cv.u.x = f2bf_pack2(f0.x, f0.y);
            cv.u.y = f2bf_pack2(f0.z, f0.w);
            cv.u.z = f2bf_pack2(f1.x, f1.y);
            cv.u.w = f2bf_pack2(f1.z, f1.w);
            a = cv.s;
        }
        #pragma unroll
        for (int t = 0; t < 4; ++t) {
            int ct = (cb >> 4) + t;
            const short* bp = (const short*)Bp1 + (((kt * 8 + ct) * 16 + l16) * 4 + quad) * 8;
            short8 bL = *(const short8*)bp;
            short8 bR = *(const short8*)(bp + 128 * 128);
            accL[t] = __builtin_amdgcn_mfma_f32_16x16x32_bf16(a, bL, accL[t], 0, 0, 0);
            accR[t] = __builtin_amdgcn_mfma_f32_16x16x32_bf16(a, bR, accR[t], 0, 0, 0);
        }
    }
    #pragma unroll
    for (int t = 0; t < 4; ++t) {
        int col = cb + t * 16 + l16;
        #pragma unroll
        for (int r = 0; r < 4; ++r) {
            int row = row0 + quad * 4 + r;
            if (row < M) {
                xlbf[(size_t)row * 128 + col] = f2bf(accL[t][r]);
                xr1[(size_t)row * 128 + col]  = accR[t][r];
            }
        }
    }
}

// ---- K2: LDS-histogram count (32-bit counters, 4 ranges) ⊕ fused xl+xr GEMM ----
__global__ __launch_bounds__(256)
void k2_count_gemms(const int* __restrict__ ei, unsigned* __restrict__ hist,
                    unsigned short* __restrict__ rank16,
                    const float* __restrict__ x, const unsigned short* __restrict__ Bp1,
                    unsigned short* __restrict__ xlbf, float* __restrict__ xr1, int M) {
    __shared__ unsigned hcnt[RSZ];            // 12500 words = 50 KB
    int b = blockIdx.x;
    if (b < NR * NCH) {
        int r = b >> 5, c = b & 31;
        for (int i = threadIdx.x; i < RSZ; i += 256) hcnt[i] = 0;
        int nz = __syncthreads_or(ei[2 * threadIdx.x + 1]);   // barrier + layout probe (0 => int64)
        int nlo = r * RSZ, nhi = nlo + RSZ;
        int cbeg = c * CSZ, cend = cbeg + CSZ;
        for (int e = cbeg + (int)threadIdx.x; e < cend; e += 1024) {
            int dd[4];
            #pragma unroll
            for (int j = 0; j < 4; ++j) {
                int ee = e + j * 256;
                dd[j] = -1;
                if (ee < cend)
                    dd[j] = nz ? ei[N_EDGES + ee] : ei[2 * N_EDGES + 2 * ee];
            }
            #pragma unroll
            for (int j = 0; j < 4; ++j) {
                int d = dd[j];
                if (d >= nlo && d < nhi) {
                    unsigned rk = atomicAdd(&hcnt[d - nlo], 1u);
                    rank16[e + j * 256] = (unsigned short)rk;
                }
            }
        }
        __syncthreads();
        unsigned* hp = hist + (size_t)(r * NCH + c) * RSZ;
        for (int i = threadIdx.x; i < RSZ; i += 256) hp[i] = hcnt[i];
    } else {
        gemm128_both(b - NR * NCH, x, Bp1, xlbf, xr1, M);
    }
}

// ---- scan (fused; publish/spin over block sums); sums NCH chunk-counts per node,
//      emits rowptr + per-(range,chunk,node) scatter bases ----
__global__ void scan_fused(const unsigned* __restrict__ hist, int* __restrict__ rowptr,
                           int* __restrict__ esrc, int* __restrict__ bsum,
                           int* __restrict__ flags, int* __restrict__ base) {
    __shared__ int sh[256];
    int b = blockIdx.x, t = threadIdx.x, i = b * 256 + t;
    unsigned d[NCH];
    int tot = 0;
    int rr = 0, q = 0;
    if (i < N_NODES) {
        rr = i / RSZ; q = i - rr * RSZ;
        const unsigned* hp = hist + (size_t)rr * NCH * RSZ + q;
        #pragma unroll
        for (int c = 0; c < NCH; ++c) { d[c] = hp[(size_t)c * RSZ]; tot += (int)d[c]; }
    }
    int v = (i < N_NODES) ? tot + 1 : 0;
    sh[t] = v;
    __syncthreads();
    int val = v;
    for (int off = 1; off < 256; off <<= 1) {
        int add = (t >= off) ? sh[t - off] : 0;
        __syncthreads();
        val += add; sh[t] = val;
        __syncthreads();
    }
    if (t == 255) {
        bsum[b] = val;
        __threadfence();
        atomicExch(&flags[b], 1);
    }
    int contrib = 0;
    if (t < b) {
        while (atomicAdd(&flags[t], 0) == 0) {}
        contrib = atomicAdd(&bsum[t], 0);
    }
    __syncthreads();
    sh[t] = contrib;
    __syncthreads();
    #pragma unroll
    for (int off = 128; off; off >>= 1) {
        if (t < off) sh[t] += sh[t + off];
        __syncthreads();
    }
    int offset = sh[0];
    if (i < N_NODES) {
        int rp = (val - v) + offset;
        rowptr[i] = rp;
        esrc[rp] = i;       // self-loop first
        int acc = rp + 1;
        int* bp = base + (size_t)rr * NCH * RSZ + q;
        #pragma unroll
        for (int c = 0; c < NCH; ++c) { bp[(size_t)c * RSZ] = acc; acc += (int)d[c]; }
    }
    if (i == 0) rowptr[N_NODES] = E_TOT;
}

// ---- scatter: no atomics, position = base[range(dst)][chunk(e)][dst%RSZ] + rank ----
__global__ void scatter_edges(const int* __restrict__ ei, const int* __restrict__ base,
                              const unsigned short* __restrict__ rank16,
                              int* __restrict__ esrc) {
    int nz = __syncthreads_or(ei[2 * threadIdx.x + 1]);
    int i = blockIdx.x * blockDim.x + threadIdx.x;
    if (2 * i >= N_EDGES) return;
    bool has2 = (2 * i + 1 < N_EDGES);
    int s0, d0, s1 = 0, d1 = 0;
    if (nz) {
        int2 sp = *(const int2*)(ei + 2 * i);
        int2 dp = *(const int2*)(ei + N_EDGES + 2 * i);
        s0 = sp.x; s1 = sp.y; d0 = dp.x; d1 = dp.y;
    } else {
        int4 sp = *(const int4*)(ei + 4 * i);
        int4 dp = *(const int4*)(ei + 2 * N_EDGES + 4 * i);
        s0 = sp.x; s1 = sp.z; d0 = dp.x; d1 = dp.z;
    }
    unsigned rr = *(const unsigned*)(rank16 + 2 * i);
    int e0 = 2 * i, e1 = 2 * i + 1;
    int c0 = e0 / CSZ, c1 = e1 / CSZ;
    int r0 = d0 / RSZ, r1 = d1 / RSZ;
    esrc[base[((size_t)r0 * NCH + c0) * RSZ + (d0 - r0 * RSZ)] + (int)(rr & 0xffffu)] = s0;
    if (has2)
        esrc[base[((size_t)r1 * NCH + c1) * RSZ + (d1 - r1 * RSZ)] + (int)(rr >> 16)] = s1;
}

// ---- layer 2 GEMM (N=64): C0bf = bf16(A@B0), C1 = A@B1 (fp32) ----
__global__ __launch_bounds__(256)
void gemm_mfma64(const unsigned short* __restrict__ Abf, const unsigned short* __restrict__ Bp,
                 unsigned short* __restrict__ C0bf, float* __restrict__ C1, int M) {
    int w = threadIdx.x >> 6, lane = threadIdx.x & 63;
    int quad = lane >> 4, l16 = lane & 15;
    int matrix = w >> 1;
    int row0 = blockIdx.x * 32 + (w & 1) * 16;
    const unsigned short* Bm = Bp + matrix * 128 * 64;
    f32x4 acc[4];
    #pragma unroll
    for (int t = 0; t < 4; ++t) acc[t] = (f32x4){0.f, 0.f, 0.f, 0.f};
    int arow = row0 + l16;
    bool aok = arow < M;
    const short* Ap = (const short*)Abf + (size_t)arow * 128 + quad * 8;
    #pragma unroll
    for (int kt = 0; kt < 4; ++kt) {
        short8 a = (short8)0;
        if (aok) a = *(const short8*)(Ap + kt * 32);
        #pragma unroll
        for (int t = 0; t < 4; ++t) {
            const short* bp = (const short*)Bm + (((kt * 4 + t) * 16 + l16) * 4 + quad) * 8;
            short8 bfr = *(const short8*)bp;
            acc[t] = __builtin_amdgcn_mfma_f32_16x16x32_bf16(a, bfr, acc[t], 0, 0, 0);
        }
    }
    #pragma unroll
    for (int t = 0; t < 4; ++t) {
        int col = t * 16 + l16;
        #pragma unroll
        for (int r = 0; r < 4; ++r) {
            int row = row0 + quad * 4 + r;
            if (row < M) {
                if (matrix) C1[(size_t)row * 64 + col] = acc[t][r];
                else        C0bf[(size_t)row * 64 + col] = f2bf(acc[t][r]);
            }
        }
    }
}

// ---------------- Layer 1 (H=8, C=16) — 1 wave/node, unroll-2 dual-prefetch ----------------
// lrelu(t) = 0.6t + 0.4|t| (slope 0.2); 0.6/0.4 and log2(e) folded into att coeffs.
__global__ __launch_bounds__(64)
void node_fused1(const int* __restrict__ rowptr, const int* __restrict__ esrc,
                 const unsigned short* __restrict__ xlbf, const float* __restrict__ xr,
                 const float* __restrict__ att, const float* __restrict__ b1,
                 unsigned short* __restrict__ hbf) {
    int lane = threadIdx.x;                   // 0..63
    int n = blockIdx.x;                       // grid = 50000 exact
    int slot = lane >> 4;                     // 0..3
    int l = lane & 15;                        // channels 8l..8l+7
    int beg = rowptr[n], end = rowptr[n + 1];
    const float* xrp = xr + (size_t)n * 128 + 8 * l;
    float4 xra = *(const float4*)(xrp);
    float4 xrb = *(const float4*)(xrp + 4);
    float4 ata = *(const float4*)(att + 8 * l);
    float4 atb = *(const float4*)(att + 8 * l + 4);
    const float c6 = 0.6f * LOG2E, c4 = 0.4f * LOG2E;
    float4 a6, a4, b6, b4c;
    a6.x = ata.x * c6; a6.y = ata.y * c6; a6.z = ata.z * c6; a6.w = ata.w * c6;
    a4.x = ata.x * c4; a4.y = ata.y * c4; a4.z = ata.z * c4; a4.w = ata.w * c4;
    b6.x = atb.x * c6; b6.y = atb.y * c6; b6.z = atb.z * c6; b6.w = atb.w * c6;
    b4c.x = atb.x * c4; b4c.y = atb.y * c4; b4c.z = atb.z * c4; b4c.w = atb.w * c4;
    float den = 0.0f;
    float4 aa = {0, 0, 0, 0}, ab = {0, 0, 0, 0};

    const unsigned loff = 8u * (unsigned)l;
    auto ldrow = [&](unsigned s) -> uint4 {
        return *(const uint4*)(xlbf + (s * 128u + loff));   // 32-bit offset, saddr form
    };
    auto edge = [&](const uint4& u) {
        float x0 = bf_lo(u.x), x1 = bf_hi(u.x);
        float x2 = bf_lo(u.y), x3 = bf_hi(u.y);
        float x4 = bf_lo(u.z), x5 = bf_hi(u.z);
        float x6 = bf_lo(u.w), x7 = bf_hi(u.w);
        float t0 = x0 + xra.x, t1 = x1 + xra.y, t2 = x2 + xra.z, t3 = x3 + xra.w;
        float t4 = x4 + xrb.x, t5 = x5 + xrb.y, t6 = x6 + xrb.z, t7 = x7 + xrb.w;
        float v = 0.0f;
        v = __builtin_fmaf(a6.x, t0, v); v = __builtin_fmaf(a4.x, __builtin_fabsf(t0), v);
        v = __builtin_fmaf(a6.y, t1, v); v = __builtin_fmaf(a4.y, __builtin_fabsf(t1), v);
        v = __builtin_fmaf(a6.z, t2, v); v = __builtin_fmaf(a4.z, __builtin_fabsf(t2), v);
        v = __builtin_fmaf(a6.w, t3, v); v = __builtin_fmaf(a4.w, __builtin_fabsf(t3), v);
        v = __builtin_fmaf(b6.x, t4, v); v = __builtin_fmaf(b4c.x, __builtin_fabsf(t4), v);
        v = __builtin_fmaf(b6.y, t5, v); v = __builtin_fmaf(b4c.y, __builtin_fabsf(t5), v);
        v = __builtin_fmaf(b6.z, t6, v); v = __builtin_fmaf(b4c.z, __builtin_fabsf(t6), v);
        v = __builtin_fmaf(b6.w, t7, v); v = __builtin_fmaf(b4c.w, __builtin_fabsf(t7), v);
        v += __shfl_xor(v, 1);                // combine the head's two lanes
        float p = exp2f(v);
        den += p;
        aa.x = __builtin_fmaf(p, x0, aa.x); aa.y = __builtin_fmaf(p, x1, aa.y);
        aa.z = __builtin_fmaf(p, x2, aa.z); aa.w = __builtin_fmaf(p, x3, aa.w);
        ab.x = __builtin_fmaf(p, x4, ab.x); ab.y = __builtin_fmaf(p, x5, ab.y);
        ab.z = __builtin_fmaf(p, x6, ab.z); ab.w = __builtin_fmaf(p, x7, ab.w);
    };
    // prefetch indices clamp to beg (self-loop slot, always valid)
    int k0 = beg + slot;
    unsigned s0 = (unsigned)esrc[k0 < end ? k0 : beg];
    unsigned s1 = (unsigned)esrc[k0 + 4 < end ? k0 + 4 : beg];
    uint4 uA = ldrow(s0);
    uint4 uB = ldrow(s1);
    unsigned sC = (unsigned)esrc[k0 + 8 < end ? k0 + 8 : beg];
    unsigned sD = (unsigned)esrc[k0 + 12 < end ? k0 + 12 : beg];

    for (int k = k0; k < end; k += 8) {
        uint4 uC = ldrow(sC);                                    // rows 2 iters ahead
        uint4 uD = ldrow(sD);
        unsigned sE = (unsigned)esrc[k + 16 < end ? k + 16 : beg];
        unsigned sF = (unsigned)esrc[k + 20 < end ? k + 20 : beg];
        edge(uA);
        if (k + 4 < end) edge(uB);
        uA = uC; uB = uD; sC = sE; sD = sF;
    }

    #pragma unroll
    for (int off = 16; off < 64; off <<= 1) {
        aa.x += __shfl_xor(aa.x, off); aa.y += __shfl_xor(aa.y, off);
        aa.z += __shfl_xor(aa.z, off); aa.w += __shfl_xor(aa.w, off);
        ab.x += __shfl_xor(ab.x, off); ab.y += __shfl_xor(ab.y, off);
        ab.z += __shfl_xor(ab.z, off); ab.w += __shfl_xor(ab.w, off);
        den   += __shfl_xor(den, off);
    }
    if (slot == 0) {
        float inv = 1.0f / (den + SM_EPS);
        float4 b4a = *(const float4*)(b1 + 8 * l);
        float4 b4b = *(const float4*)(b1 + 8 * l + 4);
        float oa0 = fmaxf(aa.x * inv + b4a.x, 0.0f);
        float oa1 = fmaxf(aa.y * inv + b4a.y, 0.0f);
        float oa2 = fmaxf(aa.z * inv + b4a.z, 0.0f);
        float oa3 = fmaxf(aa.w * inv + b4a.w, 0.0f);
        float ob0 = fmaxf(ab.x * inv + b4b.x, 0.0f);
        float ob1 = fmaxf(ab.y * inv + b4b.y, 0.0f);
        float ob2 = fmaxf(ab.z * inv + b4b.z, 0.0f);
        float ob3 = fmaxf(ab.w * inv + b4b.w, 0.0f);
        uint4 pk;
        pk.x = f2bf_pack2(oa0, oa1);
        pk.y = f2bf_pack2(oa2, oa3);
        pk.z = f2bf_pack2(ob0, ob1);
        pk.w = f2bf_pack2(ob2, ob3);
        *(uint4*)(hbf + (size_t)n * 128 + 8 * l) = pk;
    }
}

// ---------------- Layer 2 (H=1, C=64) — 1 wave/node, unroll-2 dual-prefetch ----------------
__global__ __launch_bounds__(64)
void node_fused2(const int* __restrict__ rowptr, const int* __restrict__ esrc,
                 const unsigned short* __restrict__ xlbf, const float* __restrict__ xr,
                 const float* __restrict__ att, const float* __restrict__ b2v,
                 float* __restrict__ out_emb, unsigned short* __restrict__ embbf) {
    int lane = threadIdx.x;
    int n = blockIdx.x;
    int slot = lane >> 3;                     // 0..7
    int l = lane & 7;                         // channels 8l..8l+7
    int beg = rowptr[n], end = rowptr[n + 1];
    const float* xrp = xr + (size_t)n * 64 + 8 * l;
    float4 xra = *(const float4*)(xrp);
    float4 xrb = *(const float4*)(xrp + 4);
    float4 ata = *(const float4*)(att + 8 * l);
    float4 atb = *(const float4*)(att + 8 * l + 4);
    const float c6 = 0.6f * LOG2E, c4 = 0.4f * LOG2E;
    float4 a6, a4, b6, b4c;
    a6.x = ata.x * c6; a6.y = ata.y * c6; a6.z = ata.z * c6; a6.w = ata.w * c6;
    a4.x = ata.x * c4; a4.y = ata.y * c4; a4.z = ata.z * c4; a4.w = ata.w * c4;
    b6.x = atb.x * c6; b6.y = atb.y * c6; b6.z = atb.z * c6; b6.w = atb.w * c6;
    b4c.x = atb.x * c4; b4c.y = atb.y * c4; b4c.z = atb.z * c4; b4c.w = atb.w * c4;
    float den = 0.0f;
    float4 aa = {0, 0, 0, 0}, ab = {0, 0, 0, 0};

    const unsigned loff = 8u * (unsigned)l;
    auto ldrow = [&](unsigned s) -> uint4 {
        return *(const uint4*)(xlbf + (s * 64u + loff));     // 32-bit offset, saddr form
    };
    auto edge = [&](const uint4& u) {
        float x0 = bf_lo(u.x), x1 = bf_hi(u.x);
        float x2 = bf_lo(u.y), x3 = bf_hi(u.y);
        float x4 = bf_lo(u.z), x5 = bf_hi(u.z);
        float x6 = bf_lo(u.w), x7 = bf_hi(u.w);
        float t0 = x0 + xra.x, t1 = x1 + xra.y, t2 = x2 + xra.z, t3 = x3 + xra.w;
        float t4 = x4 + xrb.x, t5 = x5 + xrb.y, t6 = x6 + xrb.z, t7 = x7 + xrb.w;
        float v = 0.0f;
        v = __builtin_fmaf(a6.x, t0, v); v = __builtin_fmaf(a4.x, __builtin_fabsf(t0), v);
        v = __builtin_fmaf(a6.y, t1, v); v = __builtin_fmaf(a4.y, __builtin_fabsf(t1), v);
        v = __builtin_fmaf(a6.z, t2, v); v = __builtin_fmaf(a4.z, __builtin_fabsf(t2), v);
        v = __builtin_fmaf(a6.w, t3, v); v = __builtin_fmaf(a4.w, __builtin_fabsf(t3), v);
        v = __builtin_fmaf(b6.x, t4, v); v = __builtin_fmaf(b4c.x, __builtin_fabsf(t4), v);
        v = __builtin_fmaf(b6.y, t5, v); v = __builtin_fmaf(b4c.y, __builtin_fabsf(t5), v);
        v = __builtin_fmaf(b6.z, t6, v); v = __builtin_fmaf(b4c.z, __builtin_fabsf(t6), v);
        v = __builtin_fmaf(b6.w, t7, v); v = __builtin_fmaf(b4c.w, __builtin_fabsf(t7), v);
        v += __shfl_xor(v, 1);
        v += __shfl_xor(v, 2);
        v += __shfl_xor(v, 4);
        float p = exp2f(v);
        den += p;
        aa.x = __builtin_fmaf(p, x0, aa.x); aa.y = __builtin_fmaf(p, x1, aa.y);
        aa.z = __builtin_fmaf(p, x2, aa.z); aa.w = __builtin_fmaf(p, x3, aa.w);
        ab.x = __builtin_fmaf(p, x4, ab.x); ab.y = __builtin_fmaf(p, x5, ab.y);
        ab.z = __builtin_fmaf(p, x6, ab.z); ab.w = __builtin_fmaf(p, x7, ab.w);
    };
    int k0 = beg + slot;
    unsigned s0 = (unsigned)esrc[k0 < end ? k0 : beg];
    unsigned s1 = (unsigned)esrc[k0 + 8 < end ? k0 + 8 : beg];
    uint4 uA = ldrow(s0);
    uint4 uB = ldrow(s1);
    unsigned sC = (unsigned)esrc[k0 + 16 < end ? k0 + 16 : beg];
    unsigned sD = (unsigned)esrc[k0 + 24 < end ? k0 + 24 : beg];

    for (int k = k0; k < end; k += 16) {
        uint4 uC = ldrow(sC);
        uint4 uD = ldrow(sD);
        unsigned sE = (unsigned)esrc[k + 32 < end ? k + 32 : beg];
        unsigned sF = (unsigned)esrc[k + 40 < end ? k + 40 : beg];
        edge(uA);
        if (k + 8 < end) edge(uB);
        uA = uC; uB = uD; sC = sE; sD = sF;
    }

    #pragma unroll
    for (int off = 8; off < 64; off <<= 1) {
        aa.x += __shfl_xor(aa.x, off); aa.y += __shfl_xor(aa.y, off);
        aa.z += __shfl_xor(aa.z, off); aa.w += __shfl_xor(aa.w, off);
        ab.x += __shfl_xor(ab.x, off); ab.y += __shfl_xor(ab.y, off);
        ab.z += __shfl_xor(ab.z, off); ab.w += __shfl_xor(ab.w, off);
        den   += __shfl_xor(den, off);
    }
    if (slot == 0) {
        float inv = 1.0f / (den + SM_EPS);
        float4 b4a = *(const float4*)(b2v + 8 * l);
        float4 b4b = *(const float4*)(b2v + 8 * l + 4);
        float4 ea, eb;
        ea.x = aa.x * inv + b4a.x; ea.y = aa.y * inv + b4a.y;
        ea.z = aa.z * inv + b4a.z; ea.w = aa.w * inv + b4a.w;
        eb.x = ab.x * inv + b4b.x; eb.y = ab.y * inv + b4b.y;
        eb.z = ab.z * inv + b4b.z; eb.w = ab.w * inv + b4b.w;
        float* op = out_emb + (size_t)n * 64 + 8 * l;
        *(float4*)(op)     = ea;
        *(float4*)(op + 4) = eb;
        uint4 pk;
        pk.x = f2bf_pack2(ea.x, ea.y);
        pk.y = f2bf_pack2(ea.z, ea.w);
        pk.z = f2bf_pack2(eb.x, eb.y);
        pk.w = f2bf_pack2(eb.z, eb.w);
        *(uint4*)(embbf + (size_t)n * 64 + 8 * l) = pk;
    }
}

// ---------------- Classifier via MFMA ----------------
__global__ __launch_bounds__(256)
void cls_mfma(const unsigned short* __restrict__ embbf, const unsigned short* __restrict__ Wc1p,
              const float* __restrict__ bc1, const float* __restrict__ Wc2,
              const float* __restrict__ bc2, float* __restrict__ out_logits) {
    __shared__ float part[2][16][2][2];       // [rowhalf][row16][colhalf][class]
    int w = threadIdx.x >> 6, lane = threadIdx.x & 63;
    int quad = lane >> 4, l16 = lane & 15;
    int rowhalf = w & 1, colhalf = w >> 1;
    int row0 = blockIdx.x * 32 + rowhalf * 16;
    int cb = colhalf * 64;
    f32x4 acc[4];
    #pragma unroll
    for (int t = 0; t < 4; ++t) acc[t] = (f32x4){0.f, 0.f, 0.f, 0.f};
    int arow = row0 + l16;
    bool aok = arow < N_NODES;
    const short* Ap = (const short*)embbf + (size_t)arow * 64 + quad * 8;
    #pragma unroll
    for (int kt = 0; kt < 2; ++kt) {
        short8 a = (short8)0;
        if (aok) a = *(const short8*)(Ap + kt * 32);
        #pragma unroll
        for (int t = 0; t < 4; ++t) {
            int ct = colhalf * 4 + t;
            const short* bp = (const short*)Wc1p + (((kt * 8 + ct) * 16 + l16) * 4 + quad) * 8;
            short8 bfr = *(const short8*)bp;
            acc[t] = __builtin_amdgcn_mfma_f32_16x16x32_bf16(a, bfr, acc[t], 0, 0, 0);
        }
    }
    float p0[4] = {0, 0, 0, 0}, p1[4] = {0, 0, 0, 0};
    #pragma unroll
    for (int t = 0; t < 4; ++t) {
        int col = cb + t * 16 + l16;
        float w2a = Wc2[2 * col], w2b = Wc2[2 * col + 1];
        float bc = bc1[col];
        #pragma unroll
        for (int r = 0; r < 4; ++r) {
            float tv = fmaxf(acc[t][r] + bc, 0.0f);
            p0[r] += tv * w2a;
            p1[r] += tv * w2b;
        }
    }
    #pragma unroll
    for (int off = 1; off < 16; off <<= 1) {
        #pragma unroll
        for (int r = 0; r < 4; ++r) {
            p0[r] += __shfl_xor(p0[r], off);
            p1[r] += __shfl_xor(p1[r], off);
        }
    }
    if (l16 == 0) {
        #pragma unroll
        for (int r = 0; r < 4; ++r) {
            part[rowhalf][quad * 4 + r][colhalf][0] = p0[r];
            part[rowhalf][quad * 4 + r][colhalf][1] = p1[r];
        }
    }
    __syncthreads();
    int t = threadIdx.x;
    if (t < 64) {
        int row = t >> 1, c = t & 1;
        int rh = row >> 4, r16 = row & 15;
        float s = part[rh][r16][0][c] + part[rh][r16][1][c] + bc2[c];
        int n = blockIdx.x * 32 + row;
        if (n < N_NODES) out_logits[(size_t)n * 2 + c] = s;
    }
}

extern "C" void kernel_launch(void* const* d_in, const int* in_sizes, int n_in,
                              void* d_out, int out_size, void* d_ws, size_t ws_size,
                              hipStream_t stream) {
    const float* x    = (const float*)d_in[0];
    const int*   ei   = (const int*)d_in[1];
    const float* Wl1  = (const float*)d_in[3];
    const float* Wr1  = (const float*)d_in[4];
    const float* att1 = (const float*)d_in[5];
    const float* b1   = (const float*)d_in[6];
    const float* Wl2  = (const float*)d_in[7];
    const float* Wr2  = (const float*)d_in[8];
    const float* att2 = (const float*)d_in[9];
    const float* b2   = (const float*)d_in[10];
    const float* Wc1  = (const float*)d_in[15];
    const float* bc1  = (const float*)d_in[16];
    const float* Wc2  = (const float*)d_in[17];
    const float* bc2  = (const float*)d_in[18];

    float* ws = (float*)d_ws;
    int* rowptr = (int*)ws + 50000;                //  50000 .. 100016
    int* esrc   = rowptr + 50016;                  // 100016 .. 950016
    int* bsum   = esrc + 850000;                   // 950016 .. 950272
    int* flags  = bsum + 256;                      // 950272 .. 950528
    unsigned short* rank16 = (unsigned short*)(flags + 256);   // 950528 .. 1350528 (400000 words)
    float* xr1           = ws + 1400448;                       // 6.4M words (layer2 xr2 in first 3.2M)
    unsigned short* xlbf = (unsigned short*)(ws + 7800448);    // 3.2M words (layer2 xl2 reuses)
    unsigned short* hbf  = (unsigned short*)(ws + 11000448);   // 3.2M words
    // hist/base overlay the hbf region: both dead before node_fused1 writes hbf.
    unsigned* hist = (unsigned*)(ws + 11000448);               // 1.6M words (128 blocks x 12500)
    int* base      = (int*)(ws + 12600448);                    // 1.6M words (.. 14200448)
    unsigned short* Bp1   = (unsigned short*)(ws + 14200448);  // .. 14216832
    unsigned short* Bp2   = (unsigned short*)(ws + 14216832);  // .. 14225024
    unsigned short* Wc1p  = (unsigned short*)(ws + 14225024);  // .. 14229120
    unsigned short* embbf = (unsigned short*)(ws + 14229120);  // 1.6M words
    // total ≈ 15.83M words ≈ 63 MB (unchanged)

    float* out_emb    = (float*)d_out;
    float* out_logits = out_emb + (size_t)N_NODES * 64;

    // ---- prep: pack Bp1/Bp2/Wc1p, zero flags (hist needs no zeroing: fully overwritten) ----
    prep<<<225, 256, 0, stream>>>(Wl1, Wr1, Wl2, Wr2, Wc1, Bp1, Bp2, Wc1p, flags);

    // ---- K2: LDS-hist count (4 ranges x 32 chunks, 32-bit counters) ⊕ fused xl+xr GEMM ----
    k2_count_gemms<<<NR * NCH + 1563, 256, 0, stream>>>(ei, hist, rank16, x, Bp1, xlbf, xr1, N_NODES);

    // ---- scan (sums 32 chunk counts/node, emits rowptr + base table) ----
    scan_fused<<<SCAN_B, 256, 0, stream>>>(hist, rowptr, esrc, bsum, flags, base);

    // ---- scatter (atomic-free) ----
    scatter_edges<<<1563, 256, 0, stream>>>(ei, base, rank16, esrc);

    // ---- layer 1 node pass: 1 wave per node, independent retirement ----
    node_fused1<<<50000, 64, 0, stream>>>(rowptr, esrc, xlbf, xr1, att1, b1, hbf);

    // ---- layer 2 ----
    gemm_mfma64<<<1563, 256, 0, stream>>>(hbf, Bp2, xlbf, xr1, N_NODES);
    node_fused2<<<50000, 64, 0, stream>>>(rowptr, esrc, xlbf, xr1, att2, b2, out_emb, embbf);

    // ---- classifier (MFMA) ----
    cls_mfma<<<1563, 256, 0, stream>>>(embbf, Wc1p, bc1, Wc2, bc2, out_logits);
}